// Round 14
// baseline (244.879 us; speedup 1.0000x reference)
//
#include <hip/hip_runtime.h>
#include <hip/hip_bf16.h>

#define B_SZ 64
#define T_SZ 2048
#define EPROJS 512
#define DUNITS 1024
#define ATT_DIM 320
#define NCH 10
#define KFILT 201
#define PAD 100

typedef __attribute__((ext_vector_type(8))) __bf16 bf16x8;
typedef __attribute__((ext_vector_type(4))) float f32x4;
typedef __attribute__((ext_vector_type(8))) unsigned short u16x8;

__device__ __forceinline__ unsigned short f2b(float f) {
    __bf16 h = (__bf16)f;
    return __builtin_bit_cast(unsigned short, h);
}

// ---------- fused front kernel: cvt_wenc | dec_feat | conv (independent works) ----------
__global__ void front_k(const float* __restrict__ W_enc, unsigned short* __restrict__ wbf,
                        const float* __restrict__ dec_z, const float* __restrict__ W_dec,
                        const float* __restrict__ b_enc, float* __restrict__ df,
                        const float* __restrict__ ap, const float* __restrict__ cw,
                        float* __restrict__ conv_out)
{
    __shared__ float s_ap[T_SZ];
    __shared__ float s_cw[KFILT];
    int blk = blockIdx.x, tid = threadIdx.x;

    if (blk < 160) {                       // ---- cvt_wenc ----
        int i = (blk * 256 + tid) * 4;
        float4 v = *(const float4*)(W_enc + i);
        ushort4 o;
        o.x = f2b(v.x); o.y = f2b(v.y); o.z = f2b(v.z); o.w = f2b(v.w);
        *(ushort4*)(wbf + i) = o;
    } else if (blk < 240) {                // ---- dec_feat ----
        int idx = (blk - 160) * 256 + tid; // [0, 20480)
        int b = idx / ATT_DIM, a = idx - b * ATT_DIM;
        const float4* z = (const float4*)(dec_z + b * DUNITS);
        const float4* w = (const float4*)(W_dec + (size_t)a * DUNITS);
        float s = b_enc[a];
        #pragma unroll 4
        for (int d = 0; d < DUNITS / 4; ++d) {
            float4 zv = z[d], wv = w[d];
            s += zv.x * wv.x + zv.y * wv.y + zv.z * wv.z + zv.w * wv.w;
        }
        df[b * ATT_DIM + a] = s;
    } else {                               // ---- conv ----
        int cb = blk - 240;                // [0, 640)
        int b = cb / NCH, c = cb - b * NCH;
        for (int i = tid; i < T_SZ; i += 256) s_ap[i] = ap[b * T_SZ + i];
        for (int i = tid; i < KFILT; i += 256) s_cw[i] = cw[c * KFILT + i];
        __syncthreads();
        for (int j = 0; j < T_SZ / 256; ++j) {
            int t = tid + j * 256;
            int klo = max(0, PAD - t);
            int khi = min(KFILT, T_SZ + PAD - t);
            float s = 0.f;
            for (int k = klo; k < khi; ++k) s += s_ap[t - PAD + k] * s_cw[k];
            conv_out[((size_t)(b * NCH + c)) * T_SZ + t] = s;
        }
    }
}

// ---------- energy kernel: SWAPPED operands — A = W (from L2), B = enc (LDS bf16) ----------
// 10 waves; wave w owns att rows [32w, 32w+32) as A-fragments straight from L2 (no LDS).
// enc chunk [128 t][32 k] converted f32->bf16 ONCE and staged granule-major in LDS
// (granule i = g*128 + row holds enc[t0+row][k0+g*8..+8]); each wave reads 8 B-frags/chunk.
// Mechanics kept from r8: write-late staging, lgkmcnt-only barrier, all-LDS epilogue,
// masked-block early-exit. acc = 16 f32x4.
__global__ __launch_bounds__(640, 2) void energy_k(
    const float* __restrict__ enc, const unsigned short* __restrict__ wbf,
    const float* __restrict__ df, const float* __restrict__ att_conv,
    const float* __restrict__ W_att, const float* __restrict__ W_g,
    const int* __restrict__ len, float* __restrict__ e_out)
{
    __shared__ unsigned short sEnc[2][512 * 8];   // 2 x 8 KB
    __shared__ float sDf[ATT_DIM], sWg[ATT_DIM], sWatt[ATT_DIM * NCH], sConv[NCH * 128];
    __shared__ float sE[10][128];                 // per-wave partial energies

    int tid = threadIdx.x;
    int lane = tid & 63, wave = tid >> 6;         // 10 waves
    int b = blockIdx.x >> 4;
    int t0 = (blockIdx.x & 15) << 7;              // BM(time) = 128

    if (t0 >= len[b]) return;   // masked tile: softmax masks by index, content irrelevant

    int m15 = lane & 15, kg = lane >> 4;
    // W A-frag pointers: att rows wave*32 + mt*16 + m15, k-offset kg*8 (bf16, L2-resident)
    const unsigned short* wq0 = wbf + (size_t)(wave * 32 + m15) * EPROJS + kg * 8;
    const unsigned short* wq1 = wq0 + 16 * EPROJS;

    // staging coords (threads 0..511): granule tid -> g = tid>>7, row = tid&127
    bool doStage = tid < 512;
    int srow = tid & 127, sg = tid >> 7;
    const float* sp = enc + ((size_t)b * T_SZ + t0 + srow) * EPROJS + sg * 8;

    // ---- prologue: stage enc chunk 0 (f32 -> bf16) into buffer 0 ----
    if (doStage) {
        float4 f0 = *(const float4*)(sp);
        float4 f1 = *(const float4*)(sp + 4);
        u16x8 v;
        v[0] = f2b(f0.x); v[1] = f2b(f0.y); v[2] = f2b(f0.z); v[3] = f2b(f0.w);
        v[4] = f2b(f1.x); v[5] = f2b(f1.y); v[6] = f2b(f1.z); v[7] = f2b(f1.w);
        *(u16x8*)(&sEnc[0][tid * 8]) = v;
    }

    for (int i = tid; i < ATT_DIM; i += 640) { sDf[i] = df[b * ATT_DIM + i]; sWg[i] = W_g[i]; }
    for (int i = tid; i < ATT_DIM * NCH; i += 640) sWatt[i] = W_att[i];
    for (int i = tid; i < NCH * 128; i += 640)
        sConv[i] = att_conv[((size_t)(b * NCH + (i >> 7))) * T_SZ + t0 + (i & 127)];

    f32x4 acc[16];   // [mt*8 + nt]
    #pragma unroll
    for (int n = 0; n < 16; ++n) acc[n] = (f32x4){0.f, 0.f, 0.f, 0.f};

    __syncthreads();   // chunk 0 + front matter visible

    for (int t = 0; t < 16; ++t) {
        int cur = t & 1;
        int k0 = t * 32;
        int kn = ((t + 1) & 15) * 32;

        // 1) issue next chunk's enc loads (f32, 8 regs; wraps on last iter — harmless)
        float4 f0, f1;
        if (doStage) {
            f0 = *(const float4*)(sp + kn);
            f1 = *(const float4*)(sp + kn + 4);
        }
        // 2) W A-frags for chunk t (L2-hot)
        bf16x8 wa0 = *(const bf16x8*)(wq0 + k0);
        bf16x8 wa1 = *(const bf16x8*)(wq1 + k0);

        // 3) compute: 8 time-tiles; one B-frag read feeds both att-tiles
        const unsigned short* se = sEnc[cur];
        #pragma unroll
        for (int nt = 0; nt < 8; ++nt) {
            bf16x8 bf = *(const bf16x8*)(se + ((kg << 7) + nt * 16 + m15) * 8);
            acc[nt]     = __builtin_amdgcn_mfma_f32_16x16x32_bf16(wa0, bf, acc[nt],     0, 0, 0);
            acc[8 + nt] = __builtin_amdgcn_mfma_f32_16x16x32_bf16(wa1, bf, acc[8 + nt], 0, 0, 0);
        }

        // 4) write-late: cvt + store next chunk into the other buffer
        if (doStage) {
            u16x8 v;
            v[0] = f2b(f0.x); v[1] = f2b(f0.y); v[2] = f2b(f0.z); v[3] = f2b(f0.w);
            v[4] = f2b(f1.x); v[5] = f2b(f1.y); v[6] = f2b(f1.z); v[7] = f2b(f1.w);
            *(u16x8*)(&sEnc[cur ^ 1][tid * 8]) = v;
        }

        // 5) my ds ops complete -> barrier (no vmcnt drain)
        asm volatile("s_waitcnt lgkmcnt(0)" ::: "memory");
        __builtin_amdgcn_s_barrier();
    }

    // epilogue: per time-col partial over this wave's 32 att rows.
    // C/D: col (=time) = l&15, row (=att) = (l>>4)*4 + r per tile.
    #pragma unroll
    for (int nt = 0; nt < 8; ++nt) {
        int tl = nt * 16 + m15;
        float s = 0.f;
        #pragma unroll
        for (int mt = 0; mt < 2; ++mt) {
            #pragma unroll
            for (int r = 0; r < 4; ++r) {
                int att = wave * 32 + mt * 16 + kg * 4 + r;
                float v = acc[mt * 8 + nt][r] + sDf[att];
                float afeat = 0.f;
                #pragma unroll
                for (int c = 0; c < NCH; ++c) afeat += sWatt[att * NCH + c] * sConv[c * 128 + tl];
                v += afeat;
                v = fminf(fmaxf(v, -15.f), 15.f);
                float e2 = __expf(2.f * v);
                s += sWg[att] * ((e2 - 1.f) / (e2 + 1.f));
            }
        }
        s += __shfl_xor(s, 16); s += __shfl_xor(s, 32);   // sum kg groups (same time col)
        if (kg == 0) sE[wave][tl] = s;
    }
    __syncthreads();
    if (tid < 128) {
        float s = 0.f;
        #pragma unroll
        for (int w = 0; w < 10; ++w) s += sE[w][tid];
        e_out[b * T_SZ + t0 + tid] = s;
    }
}

// ---------- fused softmax + context partial (r13, unchanged) ----------
__global__ void softmax_ctx_k(const float* __restrict__ e, const int* __restrict__ len,
                              const float* __restrict__ enc,
                              float* __restrict__ w_out, float* __restrict__ part) {
    int b = blockIdx.x, tc = blockIdx.y, tid = threadIdx.x;
    int lane = tid & 63, wave = tid >> 6;
    int L = len[b];
    int tb = tc * 128;
    int half = tid >> 7;
    int c4 = tid & 127;
    float* po = part + ((size_t)(b * 32 + tc * 2 + half)) * EPROJS + c4 * 4;

    if (tb >= L) {
        if (tid < 128) w_out[b * T_SZ + tb + tid] = 0.f;
        *(f32x4*)po = (f32x4){0.f, 0.f, 0.f, 0.f};
        return;
    }

    float ev[8];
    float m = -1e30f;
    #pragma unroll
    for (int i = 0; i < 8; ++i) {
        int t = tid + i * 256;
        float x = e[b * T_SZ + t];
        if (t >= L) x = -1e30f;
        ev[i] = x;
        m = fmaxf(m, x);
    }
    #pragma unroll
    for (int o = 32; o > 0; o >>= 1) m = fmaxf(m, __shfl_xor(m, o));
    __shared__ float sred[4];
    if (lane == 0) sred[wave] = m;
    __syncthreads();
    m = fmaxf(fmaxf(sred[0], sred[1]), fmaxf(sred[2], sred[3]));

    float sum = 0.f;
    #pragma unroll
    for (int i = 0; i < 8; ++i) sum += __expf(2.f * (ev[i] - m));
    #pragma unroll
    for (int o = 32; o > 0; o >>= 1) sum += __shfl_xor(sum, o);
    __shared__ float sred2[4];
    if (lane == 0) sred2[wave] = sum;
    __syncthreads();
    sum = sred2[0] + sred2[1] + sred2[2] + sred2[3];
    float inv = 1.f / sum;

    if (tid < 128) {
        int t = tb + tid;
        float wv = 0.f;
        if (t < L) wv = __expf(2.f * (e[b * T_SZ + t] - m)) * inv;
        w_out[b * T_SZ + t] = wv;
    }

    f32x4 s = (f32x4){0.f, 0.f, 0.f, 0.f};
    #pragma unroll 4
    for (int i = half; i < 128; i += 2) {
        int t = tb + i;
        float ee = e[b * T_SZ + t];
        float wv = (t < L) ? __expf(2.f * (ee - m)) * inv : 0.f;
        f32x4 v = *(const f32x4*)(enc + ((size_t)b * T_SZ + t) * EPROJS + c4 * 4);
        s += wv * v;
    }
    *(f32x4*)po = s;
}

__global__ void ctx_reduce_k(const float* __restrict__ part, float* __restrict__ c_out) {
    int b = blockIdx.x;
    int c4 = threadIdx.x;
    f32x4 s = (f32x4){0.f, 0.f, 0.f, 0.f};
    #pragma unroll
    for (int tc = 0; tc < 32; ++tc)
        s += *(const f32x4*)(part + ((size_t)(b * 32 + tc)) * EPROJS + c4 * 4);
    *(f32x4*)(c_out + b * EPROJS + c4 * 4) = s;
}

extern "C" void kernel_launch(void* const* d_in, const int* in_sizes, int n_in,
                              void* d_out, int out_size, void* d_ws, size_t ws_size,
                              hipStream_t stream) {
    const float* enc      = (const float*)d_in[0];
    const int*   len      = (const int*)d_in[1];
    const float* dec_z    = (const float*)d_in[2];
    const float* att_prev = (const float*)d_in[3];
    const float* W_enc    = (const float*)d_in[4];
    const float* b_enc    = (const float*)d_in[5];
    const float* W_dec    = (const float*)d_in[6];
    const float* W_att    = (const float*)d_in[7];
    const float* conv_w   = (const float*)d_in[8];
    const float* W_g      = (const float*)d_in[9];
    // b_g (d_in[10]) == 0 and softmax-invariant anyway.

    char* ws = (char*)d_ws;
    size_t off = 0;
    unsigned short* wbf = (unsigned short*)(ws + off); off += (size_t)ATT_DIM * EPROJS * 2;
    float* e_buf  = (float*)(ws + off); off += (size_t)B_SZ * T_SZ * 4;
    float* dfb    = (float*)(ws + off); off += (size_t)B_SZ * ATT_DIM * 4;
    float* att_cv = (float*)(ws + off); off += (size_t)B_SZ * NCH * T_SZ * 4;
    float* part   = (float*)(ws + off); off += (size_t)B_SZ * 32 * EPROJS * 4;

    float* c_out = (float*)d_out;                    // [64][512]
    float* w_out = (float*)d_out + B_SZ * EPROJS;    // [64][2048]

    front_k<<<dim3(880), dim3(256), 0, stream>>>(W_enc, wbf, dec_z, W_dec, b_enc, dfb,
                                                 att_prev, conv_w, att_cv);
    energy_k<<<dim3(B_SZ * 16), dim3(640), 0, stream>>>(enc, wbf, dfb, att_cv, W_att, W_g, len, e_buf);
    softmax_ctx_k<<<dim3(B_SZ, 16), dim3(256), 0, stream>>>(e_buf, len, enc, w_out, part);
    ctx_reduce_k<<<dim3(B_SZ), dim3(128), 0, stream>>>(part, c_out);
}